// Round 3
// baseline (715.346 us; speedup 1.0000x reference)
//
#include <hip/hip_runtime.h>
#include <cstdint>

#define B_ 128
#define T_ 1024
#define D_ 256
#define U_ 48

// ---------------------------------------------------------------------------
// K1: logits[row][u] = sum_d x[row][d] * kernel[d][u] + bias[u]
// rows = B*T = 131072. One thread per row; kernel matrix staged in LDS and
// read at wave-uniform addresses (LDS broadcast, conflict-free).
// ---------------------------------------------------------------------------
__global__ __launch_bounds__(256) void k_logits(const float* __restrict__ x,
                                                const float* __restrict__ kern,
                                                const float* __restrict__ bias,
                                                float* __restrict__ logits) {
    __shared__ float K[D_ * U_];   // 48 KB
    __shared__ float bsh[U_];
    const int tid = threadIdx.x;
    for (int i = tid; i < D_ * U_; i += 256) K[i] = kern[i];
    if (tid < U_) bsh[tid] = bias[tid];
    __syncthreads();

    const long row = (long)blockIdx.x * 256 + tid;       // 0..131071, exact
    const float4* xr = (const float4*)(x + row * D_);

    float acc[U_];
#pragma unroll
    for (int u = 0; u < U_; ++u) acc[u] = 0.0f;

    float4 xv = xr[0];
#pragma unroll 1
    for (int d4 = 0; d4 < D_ / 4; ++d4) {
        float4 xnext;
        if (d4 + 1 < D_ / 4) xnext = xr[d4 + 1];
        const float xc[4] = {xv.x, xv.y, xv.z, xv.w};
#pragma unroll
        for (int c = 0; c < 4; ++c) {
            const float4* kp = (const float4*)&K[(d4 * 4 + c) * U_];
            const float xs = xc[c];
#pragma unroll
            for (int u4 = 0; u4 < U_ / 4; ++u4) {
                float4 kv = kp[u4];
                acc[u4 * 4 + 0] += xs * kv.x;
                acc[u4 * 4 + 1] += xs * kv.y;
                acc[u4 * 4 + 2] += xs * kv.z;
                acc[u4 * 4 + 3] += xs * kv.w;
            }
        }
        xv = xnext;
    }

    float4* o4 = (float4*)(logits + row * U_);
#pragma unroll
    for (int i = 0; i < U_ / 4; ++i) {
        float4 v;
        v.x = acc[i * 4 + 0] + bsh[i * 4 + 0];
        v.y = acc[i * 4 + 1] + bsh[i * 4 + 1];
        v.z = acc[i * 4 + 2] + bsh[i * 4 + 2];
        v.w = acc[i * 4 + 3] + bsh[i * 4 + 3];
        o4[i] = v;
    }
}

// Pin a 16-element slice of tc[] into VGPRs (empty asm, "+v" constraints).
// R2 evidence: allocator chose 36 VGPRs -> tc demoted -> each candidate
// became a dependent reload chain (~14 cyc) with no TLP to hide it
// (1 wave/SIMD). Pinning forces residency; candidates then pipeline at
// issue rate.
#define PIN16(a, i)                                                         \
    asm volatile("" : "+v"(a[i + 0]), "+v"(a[i + 1]), "+v"(a[i + 2]),       \
                      "+v"(a[i + 3]), "+v"(a[i + 4]), "+v"(a[i + 5]),       \
                      "+v"(a[i + 6]), "+v"(a[i + 7]), "+v"(a[i + 8]),       \
                      "+v"(a[i + 9]), "+v"(a[i + 10]), "+v"(a[i + 11]),     \
                      "+v"(a[i + 12]), "+v"(a[i + 13]), "+v"(a[i + 14]),    \
                      "+v"(a[i + 15]))

// ---------------------------------------------------------------------------
// K2: Viterbi forward, max-only. One wave per batch. lane u holds state[u];
// state[v] broadcast via v_readlane; trans column u pinned in VGPRs.
// Prefetch depth 4 on logit rows. delta_t overwrites logits in place.
// ---------------------------------------------------------------------------
__global__ __launch_bounds__(64, 1) void k_forward(const float* __restrict__ trans,
                                                   float* __restrict__ delta) {
    const int lane = threadIdx.x;
    const int b = blockIdx.x;
    const int u = (lane < U_) ? lane : (U_ - 1);

    float tc[U_];
#pragma unroll
    for (int v = 0; v < U_; ++v) tc[v] = trans[v * U_ + u];  // column u

    float* base = delta + (long)b * T_ * U_;
    float state = base[u];            // delta_0 = logits row 0

    float pf[4];
#pragma unroll
    for (int i = 0; i < 4; ++i) pf[i] = base[(1 + i) * U_ + u];  // rows 1..4

#pragma unroll 1
    for (int tb = 1; tb < T_; tb += 4) {
        PIN16(tc, 0);
        PIN16(tc, 16);
        PIN16(tc, 32);
#pragma unroll
        for (int j = 0; j < 4; ++j) {
            const int t = tb + j;
            if (t < T_) {
                const float logit = pf[j];
                int tp = t + 4;
                if (tp > T_ - 1) tp = T_ - 1;
                pf[j] = base[(long)tp * U_ + u];     // refill ring slot j

                const int sb = __float_as_int(state);
                float m0 = -3.0e38f, m1 = -3.0e38f, m2 = -3.0e38f, m3 = -3.0e38f;
#pragma unroll
                for (int v = 0; v < U_; v += 8) {
                    float c0 = __int_as_float(__builtin_amdgcn_readlane(sb, v + 0)) + tc[v + 0];
                    float c1 = __int_as_float(__builtin_amdgcn_readlane(sb, v + 1)) + tc[v + 1];
                    float c2 = __int_as_float(__builtin_amdgcn_readlane(sb, v + 2)) + tc[v + 2];
                    float c3 = __int_as_float(__builtin_amdgcn_readlane(sb, v + 3)) + tc[v + 3];
                    float c4 = __int_as_float(__builtin_amdgcn_readlane(sb, v + 4)) + tc[v + 4];
                    float c5 = __int_as_float(__builtin_amdgcn_readlane(sb, v + 5)) + tc[v + 5];
                    float c6 = __int_as_float(__builtin_amdgcn_readlane(sb, v + 6)) + tc[v + 6];
                    float c7 = __int_as_float(__builtin_amdgcn_readlane(sb, v + 7)) + tc[v + 7];
                    m0 = fmaxf(m0, fmaxf(c0, c1));   // -> v_max3
                    m1 = fmaxf(m1, fmaxf(c2, c3));
                    m2 = fmaxf(m2, fmaxf(c4, c5));
                    m3 = fmaxf(m3, fmaxf(c6, c7));
                }
                const float m = fmaxf(fmaxf(m0, m1), fmaxf(m2, m3));
                state = logit + m;                       // exact ref op order
                if (lane < U_) base[(long)t * U_ + u] = state;
            }
        }
    }
}

// ---------------------------------------------------------------------------
// K3: backpointers recomputed in parallel over all (b,t):
//   bp[b][t][u] = argmax_v(delta[b][t-1][v] + trans[v][u]),
// strict-> ascending scan == numpy first-index tie-break. Candidates are
// bit-identical to K2's, so argmax is consistent with the stored maxes.
// (8 waves/CU of TLP hides the tc-demotion latency here — left unpinned
// on purpose; pinning would raise VGPRs and cut the TLP that hides it.)
// ---------------------------------------------------------------------------
__global__ __launch_bounds__(64, 1) void k_bp(const float* __restrict__ trans,
                                              const float* __restrict__ delta,
                                              unsigned char* __restrict__ bp) {
    const int lane = threadIdx.x;
    const int u = (lane < U_) ? lane : (U_ - 1);

    float tc[U_];
#pragma unroll
    for (int v = 0; v < U_; ++v) tc[v] = trans[v * U_ + u];

    const int NROW = B_ * (T_ - 1);   // 130944
    const int stride = gridDim.x;

    int row = blockIdx.x;
    // prefetch first row
    float dnext = 0.0f;
    if (row < NROW) {
        int b = row / (T_ - 1);
        int t = row - b * (T_ - 1) + 1;
        dnext = delta[((long)b * T_ + (t - 1)) * U_ + u];
    }
#pragma unroll 1
    for (; row < NROW; row += stride) {
        const float dv = dnext;
        const int rn = row + stride;
        if (rn < NROW) {
            int bn = rn / (T_ - 1);
            int tn = rn - bn * (T_ - 1) + 1;
            dnext = delta[((long)bn * T_ + (tn - 1)) * U_ + u];
        }
        const int db = __float_as_int(dv);
        float best = -3.4e38f;
        int bi = 0;
#pragma unroll
        for (int v = 0; v < U_; ++v) {
            float c = __int_as_float(__builtin_amdgcn_readlane(db, v)) + tc[v];
            if (c > best) { best = c; bi = v; }   // strict >: first max wins
        }
        if (lane < U_) bp[(long)row * U_ + u] = (unsigned char)bi;
    }
}

// ---------------------------------------------------------------------------
// K4: backtrace. One block per batch: stage bp[b] (48 KB) in LDS, argmax of
// final state (lane 0, strict-> ascending = first-index), chase through LDS,
// coalesced tag writeback.
// ---------------------------------------------------------------------------
__global__ __launch_bounds__(64) void k_back(const float* __restrict__ delta,
                                             const unsigned char* __restrict__ bp,
                                             float* __restrict__ out) {
    __shared__ unsigned char bpl[(T_ - 1) * U_];  // 49104 B
    __shared__ float tags[T_];                    // 4 KB
    __shared__ float fin[U_];
    const int lane = threadIdx.x;
    const int b = blockIdx.x;

    const uint32_t* src = (const uint32_t*)(bp + (long)b * (T_ - 1) * U_);
    uint32_t* dst = (uint32_t*)bpl;
    const int NW = (T_ - 1) * U_ / 4;             // 12276
    for (int i = lane; i < NW; i += 64) dst[i] = src[i];
    if (lane < U_) fin[lane] = delta[((long)b * T_ + (T_ - 1)) * U_ + lane];
    __syncthreads();

    if (lane == 0) {
        float best = fin[0];
        int tag = 0;
        for (int uu = 1; uu < U_; ++uu)
            if (fin[uu] > best) { best = fin[uu]; tag = uu; }
        tags[T_ - 1] = (float)tag;
        for (int t = T_ - 1; t >= 1; --t) {
            tag = bpl[(t - 1) * U_ + tag];
            tags[t - 1] = (float)tag;
        }
    }
    __syncthreads();

    float* o = out + (long)b * T_;
    for (int i = lane; i < T_; i += 64) o[i] = tags[i];
}

// ---------------------------------------------------------------------------
extern "C" void kernel_launch(void* const* d_in, const int* in_sizes, int n_in,
                              void* d_out, int out_size, void* d_ws, size_t ws_size,
                              hipStream_t stream) {
    const float* x     = (const float*)d_in[0];   // (B,T,D)
    const float* kern  = (const float*)d_in[1];   // (D,U)
    const float* bias  = (const float*)d_in[2];   // (U,)
    const float* trans = (const float*)d_in[3];   // (U,U)
    float* out = (float*)d_out;                   // (B,T) fp32 tags

    float* logits = (float*)d_ws;                                 // 25.2 MB, becomes delta in place
    unsigned char* bp = (unsigned char*)d_ws + (size_t)B_ * T_ * U_ * 4;  // 6.3 MB

    k_logits <<<(B_ * T_) / 256, 256, 0, stream>>>(x, kern, bias, logits);
    k_forward<<<B_,   64, 0, stream>>>(trans, logits);
    k_bp     <<<2048, 64, 0, stream>>>(trans, logits, bp);
    k_back   <<<B_,   64, 0, stream>>>(logits, bp, out);
}

// Round 4
// 696.625 us; speedup vs baseline: 1.0269x; 1.0269x over previous
//
#include <hip/hip_runtime.h>
#include <cstdint>

#define B_ 128
#define T_ 1024
#define D_ 256
#define U_ 48

// ---------------------------------------------------------------------------
// K1: logits[row][u] = sum_d x[row][d] * kernel[d][u] + bias[u]
// rows = B*T = 131072. One thread per row; kernel matrix staged in LDS and
// read at wave-uniform addresses (LDS broadcast, conflict-free).
// ---------------------------------------------------------------------------
__global__ __launch_bounds__(256) void k_logits(const float* __restrict__ x,
                                                const float* __restrict__ kern,
                                                const float* __restrict__ bias,
                                                float* __restrict__ logits) {
    __shared__ float K[D_ * U_];   // 48 KB
    __shared__ float bsh[U_];
    const int tid = threadIdx.x;
    for (int i = tid; i < D_ * U_; i += 256) K[i] = kern[i];
    if (tid < U_) bsh[tid] = bias[tid];
    __syncthreads();

    const long row = (long)blockIdx.x * 256 + tid;       // 0..131071, exact
    const float4* xr = (const float4*)(x + row * D_);

    float acc[U_];
#pragma unroll
    for (int u = 0; u < U_; ++u) acc[u] = 0.0f;

    float4 xv = xr[0];
#pragma unroll 1
    for (int d4 = 0; d4 < D_ / 4; ++d4) {
        float4 xnext;
        if (d4 + 1 < D_ / 4) xnext = xr[d4 + 1];
        const float xc[4] = {xv.x, xv.y, xv.z, xv.w};
#pragma unroll
        for (int c = 0; c < 4; ++c) {
            const float4* kp = (const float4*)&K[(d4 * 4 + c) * U_];
            const float xs = xc[c];
#pragma unroll
            for (int u4 = 0; u4 < U_ / 4; ++u4) {
                float4 kv = kp[u4];
                acc[u4 * 4 + 0] += xs * kv.x;
                acc[u4 * 4 + 1] += xs * kv.y;
                acc[u4 * 4 + 2] += xs * kv.z;
                acc[u4 * 4 + 3] += xs * kv.w;
            }
        }
        xv = xnext;
    }

    float4* o4 = (float4*)(logits + row * U_);
#pragma unroll
    for (int i = 0; i < U_ / 4; ++i) {
        float4 v;
        v.x = acc[i * 4 + 0] + bsh[i * 4 + 0];
        v.y = acc[i * 4 + 1] + bsh[i * 4 + 1];
        v.z = acc[i * 4 + 2] + bsh[i * 4 + 2];
        v.w = acc[i * 4 + 3] + bsh[i * 4 + 3];
        o4[i] = v;
    }
}

// ---------------------------------------------------------------------------
// Shared body for the Viterbi max-plus step: m = max_v(state[v] + tc[v]).
// state broadcast via v_readlane (per-lane state lives in lane v).
// ---------------------------------------------------------------------------
__device__ __forceinline__ float step_max(int sb, const float* tc) {
    float m0 = -3.0e38f, m1 = -3.0e38f, m2 = -3.0e38f, m3 = -3.0e38f;
#pragma unroll
    for (int v = 0; v < U_; v += 8) {
        float c0 = __int_as_float(__builtin_amdgcn_readlane(sb, v + 0)) + tc[v + 0];
        float c1 = __int_as_float(__builtin_amdgcn_readlane(sb, v + 1)) + tc[v + 1];
        float c2 = __int_as_float(__builtin_amdgcn_readlane(sb, v + 2)) + tc[v + 2];
        float c3 = __int_as_float(__builtin_amdgcn_readlane(sb, v + 3)) + tc[v + 3];
        float c4 = __int_as_float(__builtin_amdgcn_readlane(sb, v + 4)) + tc[v + 4];
        float c5 = __int_as_float(__builtin_amdgcn_readlane(sb, v + 5)) + tc[v + 5];
        float c6 = __int_as_float(__builtin_amdgcn_readlane(sb, v + 6)) + tc[v + 6];
        float c7 = __int_as_float(__builtin_amdgcn_readlane(sb, v + 7)) + tc[v + 7];
        m0 = fmaxf(m0, fmaxf(c0, c1));   // -> v_max3
        m1 = fmaxf(m1, fmaxf(c2, c3));
        m2 = fmaxf(m2, fmaxf(c4, c5));
        m3 = fmaxf(m3, fmaxf(c6, c7));
    }
    return fmaxf(fmaxf(m0, m1), fmaxf(m2, m3));
}

// ---------------------------------------------------------------------------
// K2: Viterbi forward, max-only. One wave per batch; lane u holds state[u].
// R3 diagnosis: in-place read/write of `delta` forced the compiler to emit
// s_waitcnt vmcnt(0) between every store and the next row load (no provable
// non-aliasing) -> full VM-queue drain -> ~920 cyc/step = one HBM round trip
// per step. Fix: logits_in and delta_out are DISTINCT restrict buffers, so
// stores never order against loads; prefetch ring depth 8 keeps 8 loads in
// flight.
// ---------------------------------------------------------------------------
__global__ __launch_bounds__(64, 1) void k_forward(const float* __restrict__ trans,
                                                   const float* __restrict__ logits,
                                                   float* __restrict__ delta) {
    const int lane = threadIdx.x;
    const int b = blockIdx.x;
    const int u = (lane < U_) ? lane : (U_ - 1);

    float tc[U_];
#pragma unroll
    for (int v = 0; v < U_; ++v) tc[v] = trans[v * U_ + u];  // column u

    const float* lin = logits + (long)b * T_ * U_;
    float* dout = delta + (long)b * T_ * U_;

    float state = lin[u];                 // delta_0 = logits row 0
    if (lane < U_) dout[u] = state;       // materialize row 0 for K3/K4

    float pf[8];
#pragma unroll
    for (int i = 0; i < 8; ++i) pf[i] = lin[(1 + i) * U_ + u];  // rows 1..8

#pragma unroll 1
    for (int tb = 1; tb < T_; tb += 8) {
#pragma unroll
        for (int j = 0; j < 8; ++j) {
            const int t = tb + j;
            if (t < T_) {
                const float logit = pf[j];
                int tp = t + 8;
                if (tp > T_ - 1) tp = T_ - 1;
                pf[j] = lin[(long)tp * U_ + u];      // refill ring slot j

                const float m = step_max(__float_as_int(state), tc);
                state = logit + m;                   // exact ref op order
                if (lane < U_) dout[(long)t * U_ + u] = state;
            }
        }
    }
}

// Fallback (in-place) variant, only used if ws_size can't fit a second
// delta buffer. Same structure as R2's kernel.
__global__ __launch_bounds__(64, 1) void k_forward_inplace(const float* __restrict__ trans,
                                                           float* __restrict__ delta) {
    const int lane = threadIdx.x;
    const int b = blockIdx.x;
    const int u = (lane < U_) ? lane : (U_ - 1);

    float tc[U_];
#pragma unroll
    for (int v = 0; v < U_; ++v) tc[v] = trans[v * U_ + u];

    float* base = delta + (long)b * T_ * U_;
    float state = base[u];

    float pf[4];
#pragma unroll
    for (int i = 0; i < 4; ++i) pf[i] = base[(1 + i) * U_ + u];

#pragma unroll 1
    for (int tb = 1; tb < T_; tb += 4) {
#pragma unroll
        for (int j = 0; j < 4; ++j) {
            const int t = tb + j;
            if (t < T_) {
                const float logit = pf[j];
                int tp = t + 4;
                if (tp > T_ - 1) tp = T_ - 1;
                pf[j] = base[(long)tp * U_ + u];
                const float m = step_max(__float_as_int(state), tc);
                state = logit + m;
                if (lane < U_) base[(long)t * U_ + u] = state;
            }
        }
    }
}

// ---------------------------------------------------------------------------
// K3: backpointers recomputed in parallel over all (b,t):
//   bp[b][t][u] = argmax_v(delta[b][t-1][v] + trans[v][u]),
// strict-> ascending scan == numpy first-index tie-break. Candidates are
// bit-identical to K2's, so argmax is consistent with the stored maxes.
// ---------------------------------------------------------------------------
__global__ __launch_bounds__(64, 1) void k_bp(const float* __restrict__ trans,
                                              const float* __restrict__ delta,
                                              unsigned char* __restrict__ bp) {
    const int lane = threadIdx.x;
    const int u = (lane < U_) ? lane : (U_ - 1);

    float tc[U_];
#pragma unroll
    for (int v = 0; v < U_; ++v) tc[v] = trans[v * U_ + u];

    const int NROW = B_ * (T_ - 1);   // 130944
    const int stride = gridDim.x;

    int row = blockIdx.x;
    float dnext = 0.0f;
    if (row < NROW) {
        int b = row / (T_ - 1);
        int t = row - b * (T_ - 1) + 1;
        dnext = delta[((long)b * T_ + (t - 1)) * U_ + u];
    }
#pragma unroll 1
    for (; row < NROW; row += stride) {
        const float dv = dnext;
        const int rn = row + stride;
        if (rn < NROW) {
            int bn = rn / (T_ - 1);
            int tn = rn - bn * (T_ - 1) + 1;
            dnext = delta[((long)bn * T_ + (tn - 1)) * U_ + u];
        }
        const int db = __float_as_int(dv);
        float best = -3.4e38f;
        int bi = 0;
#pragma unroll
        for (int v = 0; v < U_; ++v) {
            float c = __int_as_float(__builtin_amdgcn_readlane(db, v)) + tc[v];
            if (c > best) { best = c; bi = v; }   // strict >: first max wins
        }
        if (lane < U_) bp[(long)row * U_ + u] = (unsigned char)bi;
    }
}

// ---------------------------------------------------------------------------
// K4: backtrace. One block per batch: stage bp[b] (48 KB) in LDS, argmax of
// final state (lane 0, strict-> ascending = first-index), chase through LDS,
// coalesced tag writeback.
// ---------------------------------------------------------------------------
__global__ __launch_bounds__(64) void k_back(const float* __restrict__ delta,
                                             const unsigned char* __restrict__ bp,
                                             float* __restrict__ out) {
    __shared__ unsigned char bpl[(T_ - 1) * U_];  // 49104 B
    __shared__ float tags[T_];                    // 4 KB
    __shared__ float fin[U_];
    const int lane = threadIdx.x;
    const int b = blockIdx.x;

    const uint32_t* src = (const uint32_t*)(bp + (long)b * (T_ - 1) * U_);
    uint32_t* dst = (uint32_t*)bpl;
    const int NW = (T_ - 1) * U_ / 4;             // 12276
    for (int i = lane; i < NW; i += 64) dst[i] = src[i];
    if (lane < U_) fin[lane] = delta[((long)b * T_ + (T_ - 1)) * U_ + lane];
    __syncthreads();

    if (lane == 0) {
        float best = fin[0];
        int tag = 0;
        for (int uu = 1; uu < U_; ++uu)
            if (fin[uu] > best) { best = fin[uu]; tag = uu; }
        tags[T_ - 1] = (float)tag;
        for (int t = T_ - 1; t >= 1; --t) {
            tag = bpl[(t - 1) * U_ + tag];
            tags[t - 1] = (float)tag;
        }
    }
    __syncthreads();

    float* o = out + (long)b * T_;
    for (int i = lane; i < T_; i += 64) o[i] = tags[i];
}

// ---------------------------------------------------------------------------
extern "C" void kernel_launch(void* const* d_in, const int* in_sizes, int n_in,
                              void* d_out, int out_size, void* d_ws, size_t ws_size,
                              hipStream_t stream) {
    const float* x     = (const float*)d_in[0];   // (B,T,D)
    const float* kern  = (const float*)d_in[1];   // (D,U)
    const float* bias  = (const float*)d_in[2];   // (U,)
    const float* trans = (const float*)d_in[3];   // (U,U)
    float* out = (float*)d_out;                   // (B,T) fp32 tags

    const size_t NBT = (size_t)B_ * T_ * U_ * sizeof(float);  // 25,165,824 B

    float* logits = (float*)d_ws;
    const bool two_buf = ws_size >= 2 * NBT + (size_t)B_ * T_ * U_;
    float* delta = two_buf ? (float*)((char*)d_ws + NBT) : logits;
    unsigned char* bp = (unsigned char*)d_ws + (two_buf ? 2 * NBT : NBT);

    k_logits<<<(B_ * T_) / 256, 256, 0, stream>>>(x, kern, bias, logits);
    if (two_buf)
        k_forward<<<B_, 64, 0, stream>>>(trans, logits, delta);
    else
        k_forward_inplace<<<B_, 64, 0, stream>>>(trans, logits);
    k_bp  <<<2048, 64, 0, stream>>>(trans, delta, bp);
    k_back<<<B_,   64, 0, stream>>>(delta, bp, out);
}

// Round 5
// 669.810 us; speedup vs baseline: 1.0680x; 1.0400x over previous
//
#include <hip/hip_runtime.h>
#include <cstdint>

#define B_ 128
#define T_ 1024
#define D_ 256
#define U_ 48

// ---------------------------------------------------------------------------
// K1: logits[row][u] = sum_d x[row][d]*kernel[d][u] + bias[u].
// R4 model: LDS-staged kernel cost ~6.3M ds_read_b128 (~120 us). Now the
// kernel matrix is read via UNIFORM scalar loads (address depends only on
// loop counters -> s_load -> SGPR), consumed as the SGPR operand of
// v_fmac_f32. No LDS at all; x read as float4 per lane (64 rows x 16B:
// 8 KB of 128B lines, fully L1-resident across the 16 d4 iterations that
// reuse them). Accumulation order per u unchanged -> bit-identical logits.
// ---------------------------------------------------------------------------
__global__ __launch_bounds__(256) void k_logits(const float* __restrict__ x,
                                                const float* __restrict__ kern,
                                                const float* __restrict__ bias,
                                                float* __restrict__ logits) {
    const int tid = threadIdx.x;
    const long row = (long)blockIdx.x * 256 + tid;       // 0..131071
    const float4* xr = (const float4*)(x + row * D_);

    float acc[U_];
#pragma unroll
    for (int u = 0; u < U_; ++u) acc[u] = 0.0f;

#pragma unroll 1
    for (int d4 = 0; d4 < D_ / 4; ++d4) {
        const float4 xv = xr[d4];
        const float xc[4] = {xv.x, xv.y, xv.z, xv.w};
#pragma unroll
        for (int c = 0; c < 4; ++c) {
            const float* krow = kern + (size_t)(d4 * 4 + c) * U_;  // uniform addr
            const float xs = xc[c];
#pragma unroll
            for (int u = 0; u < U_; ++u)
                acc[u] += xs * krow[u];   // v_fmac_f32 vdst, sgpr, vgpr
        }
    }

    float4* o4 = (float4*)(logits + row * U_);
#pragma unroll
    for (int i = 0; i < U_ / 4; ++i) {
        float4 v;
        v.x = acc[i * 4 + 0] + bias[i * 4 + 0];   // bias uniform -> s_load
        v.y = acc[i * 4 + 1] + bias[i * 4 + 1];
        v.z = acc[i * 4 + 2] + bias[i * 4 + 2];
        v.w = acc[i * 4 + 3] + bias[i * 4 + 3];
        o4[i] = v;
    }
}

// ---------------------------------------------------------------------------
// K2: Viterbi forward, max-only. One wave per batch; lane u holds state[u].
// R4 diagnosis: v_readlane broadcast -> SGPR-write->VALU-read hazard chain
// (~740 stall cyc/step, invisible to VALUBusy). Replaced with LDS broadcast:
// state written to a parity double-buffered LDS row, read back as 12
// wave-uniform ds_read_b128 (same-address broadcast, conflict-free, pure
// VGPR dataflow, no SGPR hazards). Same-wave DS ops are in-order; single
// wave -> no barrier. Exec-mask stores dropped: lanes 48-63 clamp to u=47,
// compute the identical value, and duplicate-write the same address (benign).
// ---------------------------------------------------------------------------
__global__ __launch_bounds__(64, 1) void k_forward(const float* __restrict__ trans,
                                                   const float* __restrict__ logits,
                                                   float* __restrict__ delta) {
    __shared__ float4 sbuf[2][U_ / 4];    // [parity][12] float4 = 2x48 floats
    const int lane = threadIdx.x;
    const int b = blockIdx.x;
    const int u = (lane < U_) ? lane : (U_ - 1);

    float tc[U_];
#pragma unroll
    for (int v = 0; v < U_; ++v) tc[v] = trans[v * U_ + u];  // column u

    const float* lin = logits + (long)b * T_ * U_;
    float* dout = delta + (long)b * T_ * U_;

    float state = lin[u];                    // delta_0 = logits row 0
    dout[u] = state;                         // dup-writes benign
    ((float*)sbuf[0])[u] = state;            // t=0 has parity 0

    float pf[8];
#pragma unroll
    for (int i = 0; i < 8; ++i) pf[i] = lin[(1 + i) * U_ + u];  // rows 1..8

#pragma unroll 1
    for (int tb = 1; tb < T_; tb += 8) {
#pragma unroll
        for (int j = 0; j < 8; ++j) {
            const int t = tb + j;
            if (t < T_) {                    // uniform guard (last group: 7)
                const float logit = pf[j];
                int tp = t + 8;
                if (tp > T_ - 1) tp = T_ - 1;
                pf[j] = lin[(long)tp * U_ + u];        // refill ring slot j

                const float4* sb = (const float4*)sbuf[(t - 1) & 1];
                float n0 = -3.0e38f, n1 = -3.0e38f, n2 = -3.0e38f, n3 = -3.0e38f;
#pragma unroll
                for (int k = 0; k < U_ / 4; k += 4) {
                    float4 s0 = sb[k + 0];             // broadcast reads
                    float4 s1 = sb[k + 1];
                    float4 s2 = sb[k + 2];
                    float4 s3 = sb[k + 3];
                    n0 = fmaxf(n0, fmaxf(fmaxf(s0.x + tc[4 * k + 0],  s0.y + tc[4 * k + 1]),
                                         fmaxf(s0.z + tc[4 * k + 2],  s0.w + tc[4 * k + 3])));
                    n1 = fmaxf(n1, fmaxf(fmaxf(s1.x + tc[4 * k + 4],  s1.y + tc[4 * k + 5]),
                                         fmaxf(s1.z + tc[4 * k + 6],  s1.w + tc[4 * k + 7])));
                    n2 = fmaxf(n2, fmaxf(fmaxf(s2.x + tc[4 * k + 8],  s2.y + tc[4 * k + 9]),
                                         fmaxf(s2.z + tc[4 * k + 10], s2.w + tc[4 * k + 11])));
                    n3 = fmaxf(n3, fmaxf(fmaxf(s3.x + tc[4 * k + 12], s3.y + tc[4 * k + 13]),
                                         fmaxf(s3.z + tc[4 * k + 14], s3.w + tc[4 * k + 15])));
                }
                const float m = fmaxf(fmaxf(n0, n1), fmaxf(n2, n3));
                state = logit + m;                     // exact ref op order
                ((float*)sbuf[t & 1])[u] = state;
                dout[(long)t * U_ + u] = state;
            }
        }
    }
}

// Fallback (in-place) variant if ws can't fit a second delta buffer.
__global__ __launch_bounds__(64, 1) void k_forward_inplace(const float* __restrict__ trans,
                                                           float* __restrict__ delta) {
    __shared__ float4 sbuf[2][U_ / 4];
    const int lane = threadIdx.x;
    const int b = blockIdx.x;
    const int u = (lane < U_) ? lane : (U_ - 1);

    float tc[U_];
#pragma unroll
    for (int v = 0; v < U_; ++v) tc[v] = trans[v * U_ + u];

    float* base = delta + (long)b * T_ * U_;
    float state = base[u];
    ((float*)sbuf[0])[u] = state;

#pragma unroll 1
    for (int t = 1; t < T_; ++t) {
        const float logit = base[(long)t * U_ + u];
        const float4* sb = (const float4*)sbuf[(t - 1) & 1];
        float n0 = -3.0e38f, n1 = -3.0e38f, n2 = -3.0e38f, n3 = -3.0e38f;
#pragma unroll
        for (int k = 0; k < U_ / 4; k += 4) {
            float4 s0 = sb[k + 0], s1 = sb[k + 1], s2 = sb[k + 2], s3 = sb[k + 3];
            n0 = fmaxf(n0, fmaxf(fmaxf(s0.x + tc[4 * k + 0],  s0.y + tc[4 * k + 1]),
                                 fmaxf(s0.z + tc[4 * k + 2],  s0.w + tc[4 * k + 3])));
            n1 = fmaxf(n1, fmaxf(fmaxf(s1.x + tc[4 * k + 4],  s1.y + tc[4 * k + 5]),
                                 fmaxf(s1.z + tc[4 * k + 6],  s1.w + tc[4 * k + 7])));
            n2 = fmaxf(n2, fmaxf(fmaxf(s2.x + tc[4 * k + 8],  s2.y + tc[4 * k + 9]),
                                 fmaxf(s2.z + tc[4 * k + 10], s2.w + tc[4 * k + 11])));
            n3 = fmaxf(n3, fmaxf(fmaxf(s3.x + tc[4 * k + 12], s3.y + tc[4 * k + 13]),
                                 fmaxf(s3.z + tc[4 * k + 14], s3.w + tc[4 * k + 15])));
        }
        state = logit + fmaxf(fmaxf(n0, n1), fmaxf(n2, n3));
        ((float*)sbuf[t & 1])[u] = state;
        base[(long)t * U_ + u] = state;
    }
}

// ---------------------------------------------------------------------------
// K3: backpointers recomputed in parallel over all (b,t):
//   bp[b][t][u] = argmax_v(delta[b][t-1][v] + trans[v][u]),
// strict-> ascending scan == numpy first-index tie-break. Candidates are
// bit-identical to K2's, so argmax is consistent with the stored maxes.
// (8 waves/CU of TLP hides the readlane-hazard latency here; left as-is.)
// ---------------------------------------------------------------------------
__global__ __launch_bounds__(64, 1) void k_bp(const float* __restrict__ trans,
                                              const float* __restrict__ delta,
                                              unsigned char* __restrict__ bp) {
    const int lane = threadIdx.x;
    const int u = (lane < U_) ? lane : (U_ - 1);

    float tc[U_];
#pragma unroll
    for (int v = 0; v < U_; ++v) tc[v] = trans[v * U_ + u];

    const int NROW = B_ * (T_ - 1);   // 130944
    const int stride = gridDim.x;

    int row = blockIdx.x;
    float dnext = 0.0f;
    if (row < NROW) {
        int b = row / (T_ - 1);
        int t = row - b * (T_ - 1) + 1;
        dnext = delta[((long)b * T_ + (t - 1)) * U_ + u];
    }
#pragma unroll 1
    for (; row < NROW; row += stride) {
        const float dv = dnext;
        const int rn = row + stride;
        if (rn < NROW) {
            int bn = rn / (T_ - 1);
            int tn = rn - bn * (T_ - 1) + 1;
            dnext = delta[((long)bn * T_ + (tn - 1)) * U_ + u];
        }
        const int db = __float_as_int(dv);
        float best = -3.4e38f;
        int bi = 0;
#pragma unroll
        for (int v = 0; v < U_; ++v) {
            float c = __int_as_float(__builtin_amdgcn_readlane(db, v)) + tc[v];
            if (c > best) { best = c; bi = v; }   // strict >: first max wins
        }
        if (lane < U_) bp[(long)row * U_ + u] = (unsigned char)bi;
    }
}

// ---------------------------------------------------------------------------
// K4: backtrace. One block per batch: stage bp[b] (48 KB) in LDS, argmax of
// final state (lane 0, strict-> ascending = first-index), chase through LDS,
// coalesced tag writeback.
// ---------------------------------------------------------------------------
__global__ __launch_bounds__(64) void k_back(const float* __restrict__ delta,
                                             const unsigned char* __restrict__ bp,
                                             float* __restrict__ out) {
    __shared__ unsigned char bpl[(T_ - 1) * U_];  // 49104 B
    __shared__ float tags[T_];                    // 4 KB
    __shared__ float fin[U_];
    const int lane = threadIdx.x;
    const int b = blockIdx.x;

    const uint32_t* src = (const uint32_t*)(bp + (long)b * (T_ - 1) * U_);
    uint32_t* dst = (uint32_t*)bpl;
    const int NW = (T_ - 1) * U_ / 4;             // 12276
    for (int i = lane; i < NW; i += 64) dst[i] = src[i];
    if (lane < U_) fin[lane] = delta[((long)b * T_ + (T_ - 1)) * U_ + lane];
    __syncthreads();

    if (lane == 0) {
        float best = fin[0];
        int tag = 0;
        for (int uu = 1; uu < U_; ++uu)
            if (fin[uu] > best) { best = fin[uu]; tag = uu; }
        tags[T_ - 1] = (float)tag;
        for (int t = T_ - 1; t >= 1; --t) {
            tag = bpl[(t - 1) * U_ + tag];
            tags[t - 1] = (float)tag;
        }
    }
    __syncthreads();

    float* o = out + (long)b * T_;
    for (int i = lane; i < T_; i += 64) o[i] = tags[i];
}

// ---------------------------------------------------------------------------
extern "C" void kernel_launch(void* const* d_in, const int* in_sizes, int n_in,
                              void* d_out, int out_size, void* d_ws, size_t ws_size,
                              hipStream_t stream) {
    const float* x     = (const float*)d_in[0];   // (B,T,D)
    const float* kern  = (const float*)d_in[1];   // (D,U)
    const float* bias  = (const float*)d_in[2];   // (U,)
    const float* trans = (const float*)d_in[3];   // (U,U)
    float* out = (float*)d_out;                   // (B,T) fp32 tags

    const size_t NBT = (size_t)B_ * T_ * U_ * sizeof(float);  // 25,165,824 B

    float* logits = (float*)d_ws;
    const bool two_buf = ws_size >= 2 * NBT + (size_t)B_ * T_ * U_;
    float* delta = two_buf ? (float*)((char*)d_ws + NBT) : logits;
    unsigned char* bp = (unsigned char*)d_ws + (two_buf ? 2 * NBT : NBT);

    k_logits<<<(B_ * T_) / 256, 256, 0, stream>>>(x, kern, bias, logits);
    if (two_buf)
        k_forward<<<B_, 64, 0, stream>>>(trans, logits, delta);
    else
        k_forward_inplace<<<B_, 64, 0, stream>>>(trans, logits);
    k_bp  <<<2048, 64, 0, stream>>>(trans, delta, bp);
    k_back<<<B_,   64, 0, stream>>>(delta, bp, out);
}

// Round 6
// 528.561 us; speedup vs baseline: 1.3534x; 1.2672x over previous
//
#include <hip/hip_runtime.h>
#include <cstdint>

#define B_ 128
#define T_ 1024
#define D_ 256
#define U_ 48

// ---------------------------------------------------------------------------
// K1: logits[row][u] = sum_d x[row][d]*kernel[d][u] + bias[u].
// R5 scalar-load version regressed (~+50 us: s_load->VALU serialization).
// Back to LDS staging (uniform-address b128 reads = broadcast, conflict-free)
// but with TWO rows per thread: halves the per-wave ds_read count (the R4
// binder) and doubles FMA per staged value. Accumulation order per row is
// d-ascending, unchanged -> bit-identical logits.
// ---------------------------------------------------------------------------
__global__ __launch_bounds__(256, 1) void k_logits(const float* __restrict__ x,
                                                   const float* __restrict__ kern,
                                                   const float* __restrict__ bias,
                                                   float* __restrict__ logits) {
    __shared__ float K[D_ * U_];   // 48 KB
    __shared__ float bsh[U_];
    const int tid = threadIdx.x;
    for (int i = tid; i < D_ * U_; i += 256) K[i] = kern[i];
    if (tid < U_) bsh[tid] = bias[tid];
    __syncthreads();

    const long row0 = (long)blockIdx.x * 256 + tid;      // 0..65535
    const long row1 = row0 + (long)B_ * T_ / 2;          // +65536
    const float4* xr0 = (const float4*)(x + row0 * D_);
    const float4* xr1 = (const float4*)(x + row1 * D_);

    float a0[U_], a1[U_];
#pragma unroll
    for (int u = 0; u < U_; ++u) { a0[u] = 0.0f; a1[u] = 0.0f; }

#pragma unroll 1
    for (int d4 = 0; d4 < D_ / 4; ++d4) {
        const float4 xv0 = xr0[d4];
        const float4 xv1 = xr1[d4];
        const float xc0[4] = {xv0.x, xv0.y, xv0.z, xv0.w};
        const float xc1[4] = {xv1.x, xv1.y, xv1.z, xv1.w};
#pragma unroll
        for (int c = 0; c < 4; ++c) {
            const float4* kp = (const float4*)&K[(d4 * 4 + c) * U_];
            const float s0 = xc0[c], s1 = xc1[c];
#pragma unroll
            for (int u4 = 0; u4 < U_ / 4; ++u4) {
                float4 kv = kp[u4];
                a0[u4 * 4 + 0] += s0 * kv.x;  a1[u4 * 4 + 0] += s1 * kv.x;
                a0[u4 * 4 + 1] += s0 * kv.y;  a1[u4 * 4 + 1] += s1 * kv.y;
                a0[u4 * 4 + 2] += s0 * kv.z;  a1[u4 * 4 + 2] += s1 * kv.z;
                a0[u4 * 4 + 3] += s0 * kv.w;  a1[u4 * 4 + 3] += s1 * kv.w;
            }
        }
    }

    float4* o0 = (float4*)(logits + row0 * U_);
    float4* o1 = (float4*)(logits + row1 * U_);
#pragma unroll
    for (int i = 0; i < U_ / 4; ++i) {
        float4 v0, v1;
        v0.x = a0[i*4+0] + bsh[i*4+0];  v1.x = a1[i*4+0] + bsh[i*4+0];
        v0.y = a0[i*4+1] + bsh[i*4+1];  v1.y = a1[i*4+1] + bsh[i*4+1];
        v0.z = a0[i*4+2] + bsh[i*4+2];  v1.z = a1[i*4+2] + bsh[i*4+2];
        v0.w = a0[i*4+3] + bsh[i*4+3];  v1.w = a1[i*4+3] + bsh[i*4+3];
        o0[i] = v0;
        o1[i] = v1;
    }
}

// Max-plus body: m = max_v(state[v] + tc[v]) from an LDS float4 view.
__device__ __forceinline__ float step_max_lds(const float4* sb, const float* tc) {
    float n0 = -3.0e38f, n1 = -3.0e38f, n2 = -3.0e38f, n3 = -3.0e38f;
#pragma unroll
    for (int k = 0; k < U_ / 4; k += 4) {
        float4 s0 = sb[k + 0];
        float4 s1 = sb[k + 1];
        float4 s2 = sb[k + 2];
        float4 s3 = sb[k + 3];
        n0 = fmaxf(n0, fmaxf(fmaxf(s0.x + tc[4*k + 0],  s0.y + tc[4*k + 1]),
                             fmaxf(s0.z + tc[4*k + 2],  s0.w + tc[4*k + 3])));
        n1 = fmaxf(n1, fmaxf(fmaxf(s1.x + tc[4*k + 4],  s1.y + tc[4*k + 5]),
                             fmaxf(s1.z + tc[4*k + 6],  s1.w + tc[4*k + 7])));
        n2 = fmaxf(n2, fmaxf(fmaxf(s2.x + tc[4*k + 8],  s2.y + tc[4*k + 9]),
                             fmaxf(s2.z + tc[4*k + 10], s2.w + tc[4*k + 11])));
        n3 = fmaxf(n3, fmaxf(fmaxf(s3.x + tc[4*k + 12], s3.y + tc[4*k + 13]),
                             fmaxf(s3.z + tc[4*k + 14], s3.w + tc[4*k + 15])));
    }
    return fmaxf(fmaxf(n0, n1), fmaxf(n2, n3));
}

// ---------------------------------------------------------------------------
// K2: Viterbi forward (LDS broadcast, R5-verified). R6: strip the loop
// overhead from the critical path. Main loop = 127 guard-free groups of 8
// steps (t=1..1016): base pointers advance once per group, loads/stores use
// compile-time immediate offsets (j*192 B), LDS parity = j&1 resolves to
// static buffer selection. 7-step guarded tail (t=1017..1023).
// Group 126 prefetches rows 1017..1024; "row 1024" is the first 192 B of the
// delta region (allocated, value unused) - safe.
// ---------------------------------------------------------------------------
__global__ __launch_bounds__(64, 1) void k_forward(const float* __restrict__ trans,
                                                   const float* __restrict__ logits,
                                                   float* __restrict__ delta) {
    __shared__ float4 sbuf[2][U_ / 4];    // parity double buffer, 2x48 floats
    const int lane = threadIdx.x;
    const int b = blockIdx.x;
    const int u = (lane < U_) ? lane : (U_ - 1);

    float tc[U_];
#pragma unroll
    for (int v = 0; v < U_; ++v) tc[v] = trans[v * U_ + u];  // column u

    const float* lin = logits + (long)b * T_ * U_;
    float* dout = delta + (long)b * T_ * U_;

    float state = lin[u];                 // delta_0 = logits row 0
    dout[u] = state;                      // dup-writes (lanes 48-63) benign
    ((float*)sbuf[0])[u] = state;         // t=0 parity 0

    float pf[8];
#pragma unroll
    for (int i = 0; i < 8; ++i) pf[i] = lin[(1 + i) * U_ + u];  // rows 1..8

    const float* lp = lin + 9 * U_ + u;   // prefetch base: row tb+8 for tb=1
    float* dp = dout + 1 * U_ + u;        // store base: row tb

#pragma unroll 1
    for (int g = 0; g < 127; ++g) {       // t = 1+8g .. 8+8g  (1..1016)
#pragma unroll
        for (int j = 0; j < 8; ++j) {
            const float logit = pf[j];
            pf[j] = lp[j * U_];                       // imm offset j*192 B

            const float4* sb = sbuf[j & 1];           // parity (t-1)&1 == j&1
            const float m = step_max_lds(sb, tc);
            state = logit + m;                        // exact ref op order
            ((float*)sbuf[(j & 1) ^ 1])[u] = state;
            dp[j * U_] = state;                       // imm offset j*192 B
        }
        lp += 8 * U_;
        dp += 8 * U_;
    }

    // tail: t = 1017..1023 (7 steps); pf[0..6] hold rows 1017..1023
#pragma unroll
    for (int j = 0; j < 7; ++j) {
        const float logit = pf[j];
        const float4* sb = sbuf[j & 1];               // (t-1)=1016+j parity j&1
        const float m = step_max_lds(sb, tc);
        state = logit + m;
        ((float*)sbuf[(j & 1) ^ 1])[u] = state;
        dp[j * U_] = state;
    }
}

// Fallback (in-place) variant if ws can't fit a second delta buffer.
__global__ __launch_bounds__(64, 1) void k_forward_inplace(const float* __restrict__ trans,
                                                           float* __restrict__ delta) {
    __shared__ float4 sbuf[2][U_ / 4];
    const int lane = threadIdx.x;
    const int b = blockIdx.x;
    const int u = (lane < U_) ? lane : (U_ - 1);

    float tc[U_];
#pragma unroll
    for (int v = 0; v < U_; ++v) tc[v] = trans[v * U_ + u];

    float* base = delta + (long)b * T_ * U_;
    float state = base[u];
    ((float*)sbuf[0])[u] = state;

#pragma unroll 1
    for (int t = 1; t < T_; ++t) {
        const float logit = base[(long)t * U_ + u];
        const float m = step_max_lds(sbuf[(t - 1) & 1], tc);
        state = logit + m;
        ((float*)sbuf[t & 1])[u] = state;
        base[(long)t * U_ + u] = state;
    }
}

// ---------------------------------------------------------------------------
// K3: backpointers recomputed in parallel over all (b,t):
//   bp[b][t][u] = argmax_v(delta[b][t-1][v] + trans[v][u]),
// strict-> ascending scan == numpy first-index tie-break. Candidates are
// bit-identical to K2's, so argmax is consistent with the stored maxes.
// Grid 4096 (32 rows/block): 4 waves/SIMD of TLP to hide the readlane chain.
// ---------------------------------------------------------------------------
__global__ __launch_bounds__(64, 1) void k_bp(const float* __restrict__ trans,
                                              const float* __restrict__ delta,
                                              unsigned char* __restrict__ bp) {
    const int lane = threadIdx.x;
    const int u = (lane < U_) ? lane : (U_ - 1);

    float tc[U_];
#pragma unroll
    for (int v = 0; v < U_; ++v) tc[v] = trans[v * U_ + u];

    const int NROW = B_ * (T_ - 1);   // 130944
    const int stride = gridDim.x;

    int row = blockIdx.x;
    float dnext = 0.0f;
    if (row < NROW) {
        int b = row / (T_ - 1);
        int t = row - b * (T_ - 1) + 1;
        dnext = delta[((long)b * T_ + (t - 1)) * U_ + u];
    }
#pragma unroll 1
    for (; row < NROW; row += stride) {
        const float dv = dnext;
        const int rn = row + stride;
        if (rn < NROW) {
            int bn = rn / (T_ - 1);
            int tn = rn - bn * (T_ - 1) + 1;
            dnext = delta[((long)bn * T_ + (tn - 1)) * U_ + u];
        }
        const int db = __float_as_int(dv);
        float best = -3.4e38f;
        int bi = 0;
#pragma unroll
        for (int v = 0; v < U_; ++v) {
            float c = __int_as_float(__builtin_amdgcn_readlane(db, v)) + tc[v];
            if (c > best) { best = c; bi = v; }   // strict >: first max wins
        }
        if (lane < U_) bp[(long)row * U_ + u] = (unsigned char)bi;
    }
}

// ---------------------------------------------------------------------------
// K4: backtrace. One block per batch: stage bp[b] (48 KB) in LDS, argmax of
// final state (lane 0, strict-> ascending = first-index), chase through LDS,
// coalesced tag writeback.
// ---------------------------------------------------------------------------
__global__ __launch_bounds__(64) void k_back(const float* __restrict__ delta,
                                             const unsigned char* __restrict__ bp,
                                             float* __restrict__ out) {
    __shared__ unsigned char bpl[(T_ - 1) * U_];  // 49104 B
    __shared__ float tags[T_];                    // 4 KB
    __shared__ float fin[U_];
    const int lane = threadIdx.x;
    const int b = blockIdx.x;

    const uint32_t* src = (const uint32_t*)(bp + (long)b * (T_ - 1) * U_);
    uint32_t* dst = (uint32_t*)bpl;
    const int NW = (T_ - 1) * U_ / 4;             // 12276
    for (int i = lane; i < NW; i += 64) dst[i] = src[i];
    if (lane < U_) fin[lane] = delta[((long)b * T_ + (T_ - 1)) * U_ + lane];
    __syncthreads();

    if (lane == 0) {
        float best = fin[0];
        int tag = 0;
        for (int uu = 1; uu < U_; ++uu)
            if (fin[uu] > best) { best = fin[uu]; tag = uu; }
        tags[T_ - 1] = (float)tag;
        for (int t = T_ - 1; t >= 1; --t) {
            tag = bpl[(t - 1) * U_ + tag];
            tags[t - 1] = (float)tag;
        }
    }
    __syncthreads();

    float* o = out + (long)b * T_;
    for (int i = lane; i < T_; i += 64) o[i] = tags[i];
}

// ---------------------------------------------------------------------------
extern "C" void kernel_launch(void* const* d_in, const int* in_sizes, int n_in,
                              void* d_out, int out_size, void* d_ws, size_t ws_size,
                              hipStream_t stream) {
    const float* x     = (const float*)d_in[0];   // (B,T,D)
    const float* kern  = (const float*)d_in[1];   // (D,U)
    const float* bias  = (const float*)d_in[2];   // (U,)
    const float* trans = (const float*)d_in[3];   // (U,U)
    float* out = (float*)d_out;                   // (B,T) fp32 tags

    const size_t NBT = (size_t)B_ * T_ * U_ * sizeof(float);  // 25,165,824 B

    float* logits = (float*)d_ws;
    const bool two_buf = ws_size >= 2 * NBT + (size_t)B_ * T_ * U_;
    float* delta = two_buf ? (float*)((char*)d_ws + NBT) : logits;
    unsigned char* bp = (unsigned char*)d_ws + (two_buf ? 2 * NBT : NBT);

    k_logits<<<(B_ * T_ / 2) / 256, 256, 0, stream>>>(x, kern, bias, logits);
    if (two_buf)
        k_forward<<<B_, 64, 0, stream>>>(trans, logits, delta);
    else
        k_forward_inplace<<<B_, 64, 0, stream>>>(trans, logits);
    k_bp  <<<4096, 64, 0, stream>>>(trans, delta, bp);
    k_back<<<B_,   64, 0, stream>>>(delta, bp, out);
}

// Round 7
// 515.725 us; speedup vs baseline: 1.3871x; 1.0249x over previous
//
#include <hip/hip_runtime.h>
#include <cstdint>

#define B_ 128
#define T_ 1024
#define D_ 256
#define U_ 48

// ---------------------------------------------------------------------------
// K1: logits[row][u] = sum_d x[row][d]*kernel[d][u] + bias[u].
// R6 suspicion: lane i's float4 lives in a distinct 1 KB row -> wave touches
// 64 cache lines per load instr, 64 KB live set > 32 KB L1 -> up to 16x L2
// re-fetch. R7: d-blocked so each thread loads its OWN full 128 B line
// (8 float4 back-to-back) per chunk and consumes it immediately. K stays in
// LDS (uniform b128 reads = broadcast). Per-(row,u) accumulation order is
// unchanged (d-ascending).
// ---------------------------------------------------------------------------
__global__ __launch_bounds__(256, 1) void k_logits(const float* __restrict__ x,
                                                   const float* __restrict__ kern,
                                                   const float* __restrict__ bias,
                                                   float* __restrict__ logits) {
    __shared__ float K[D_ * U_];   // 48 KB
    __shared__ float bsh[U_];
    const int tid = threadIdx.x;
    for (int i = tid; i < D_ * U_; i += 256) K[i] = kern[i];
    if (tid < U_) bsh[tid] = bias[tid];
    __syncthreads();

    const long row0 = (long)blockIdx.x * 256 + tid;      // 0..65535
    const long row1 = row0 + (long)B_ * T_ / 2;          // +65536
    const float4* xr0 = (const float4*)(x + row0 * D_);
    const float4* xr1 = (const float4*)(x + row1 * D_);

    float a0[U_], a1[U_];
#pragma unroll
    for (int u = 0; u < U_; ++u) { a0[u] = 0.0f; a1[u] = 0.0f; }

#pragma unroll 1
    for (int blk = 0; blk < D_ / 32; ++blk) {            // 8 chunks of 128 B
        float4 xa[8], xb[8];
#pragma unroll
        for (int i = 0; i < 8; ++i) xa[i] = xr0[blk * 8 + i];  // own line
#pragma unroll
        for (int i = 0; i < 8; ++i) xb[i] = xr1[blk * 8 + i];  // own line

#pragma unroll
        for (int i = 0; i < 8; ++i) {
            const int d4 = blk * 8 + i;
            const float xc0[4] = {xa[i].x, xa[i].y, xa[i].z, xa[i].w};
            const float xc1[4] = {xb[i].x, xb[i].y, xb[i].z, xb[i].w};
#pragma unroll
            for (int c = 0; c < 4; ++c) {
                const float4* kp = (const float4*)&K[(d4 * 4 + c) * U_];
                const float s0 = xc0[c], s1 = xc1[c];
#pragma unroll
                for (int u4 = 0; u4 < U_ / 4; ++u4) {
                    float4 kv = kp[u4];
                    a0[u4*4+0] += s0 * kv.x;  a1[u4*4+0] += s1 * kv.x;
                    a0[u4*4+1] += s0 * kv.y;  a1[u4*4+1] += s1 * kv.y;
                    a0[u4*4+2] += s0 * kv.z;  a1[u4*4+2] += s1 * kv.z;
                    a0[u4*4+3] += s0 * kv.w;  a1[u4*4+3] += s1 * kv.w;
                }
            }
        }
    }

    float4* o0 = (float4*)(logits + row0 * U_);
    float4* o1 = (float4*)(logits + row1 * U_);
#pragma unroll
    for (int i = 0; i < U_ / 4; ++i) {
        float4 v0, v1;
        v0.x = a0[i*4+0] + bsh[i*4+0];  v1.x = a1[i*4+0] + bsh[i*4+0];
        v0.y = a0[i*4+1] + bsh[i*4+1];  v1.y = a1[i*4+1] + bsh[i*4+1];
        v0.z = a0[i*4+2] + bsh[i*4+2];  v1.z = a1[i*4+2] + bsh[i*4+2];
        v0.w = a0[i*4+3] + bsh[i*4+3];  v1.w = a1[i*4+3] + bsh[i*4+3];
        o0[i] = v0;
        o1[i] = v1;
    }
}

// Max-plus body: m = max_v(state[v] + tc[v]); LDS float4 view, float2-paired
// adds (candidate for v_pk_add_f32; bit-identical either way — IEEE adds,
// max tree reassociation is exact).
__device__ __forceinline__ float step_max_lds(const float4* sb, const float2* tc2) {
    float n0 = -3.0e38f, n1 = -3.0e38f, n2 = -3.0e38f, n3 = -3.0e38f;
#pragma unroll
    for (int k = 0; k < U_ / 4; k += 4) {
        float4 s0 = sb[k + 0];
        float4 s1 = sb[k + 1];
        float4 s2 = sb[k + 2];
        float4 s3 = sb[k + 3];
        float2 p0 = make_float2(s0.x + tc2[2*k+0].x, s0.y + tc2[2*k+0].y);
        float2 p1 = make_float2(s0.z + tc2[2*k+1].x, s0.w + tc2[2*k+1].y);
        float2 p2 = make_float2(s1.x + tc2[2*k+2].x, s1.y + tc2[2*k+2].y);
        float2 p3 = make_float2(s1.z + tc2[2*k+3].x, s1.w + tc2[2*k+3].y);
        float2 p4 = make_float2(s2.x + tc2[2*k+4].x, s2.y + tc2[2*k+4].y);
        float2 p5 = make_float2(s2.z + tc2[2*k+5].x, s2.w + tc2[2*k+5].y);
        float2 p6 = make_float2(s3.x + tc2[2*k+6].x, s3.y + tc2[2*k+6].y);
        float2 p7 = make_float2(s3.z + tc2[2*k+7].x, s3.w + tc2[2*k+7].y);
        n0 = fmaxf(n0, fmaxf(fmaxf(p0.x, p0.y), fmaxf(p1.x, p1.y)));
        n1 = fmaxf(n1, fmaxf(fmaxf(p2.x, p2.y), fmaxf(p3.x, p3.y)));
        n2 = fmaxf(n2, fmaxf(fmaxf(p4.x, p4.y), fmaxf(p5.x, p5.y)));
        n3 = fmaxf(n3, fmaxf(fmaxf(p6.x, p6.y), fmaxf(p7.x, p7.y)));
    }
    return fmaxf(fmaxf(n0, n1), fmaxf(n2, n3));
}

// ---------------------------------------------------------------------------
// K2: Viterbi forward (LDS broadcast + guard-free grouped loop, R6-verified).
// ---------------------------------------------------------------------------
__global__ __launch_bounds__(64, 1) void k_forward(const float* __restrict__ trans,
                                                   const float* __restrict__ logits,
                                                   float* __restrict__ delta) {
    __shared__ float4 sbuf[2][U_ / 4];    // parity double buffer, 2x48 floats
    const int lane = threadIdx.x;
    const int b = blockIdx.x;
    const int u = (lane < U_) ? lane : (U_ - 1);

    float2 tc2[U_ / 2];
#pragma unroll
    for (int v = 0; v < U_; v += 2) {
        tc2[v / 2].x = trans[v * U_ + u];
        tc2[v / 2].y = trans[(v + 1) * U_ + u];
    }

    const float* lin = logits + (long)b * T_ * U_;
    float* dout = delta + (long)b * T_ * U_;

    float state = lin[u];                 // delta_0 = logits row 0
    dout[u] = state;                      // dup-writes (lanes 48-63) benign
    ((float*)sbuf[0])[u] = state;         // t=0 parity 0

    float pf[8];
#pragma unroll
    for (int i = 0; i < 8; ++i) pf[i] = lin[(1 + i) * U_ + u];  // rows 1..8

    const float* lp = lin + 9 * U_ + u;   // prefetch base: row tb+8 for tb=1
    float* dp = dout + 1 * U_ + u;        // store base: row tb

#pragma unroll 1
    for (int g = 0; g < 127; ++g) {       // t = 1+8g .. 8+8g  (1..1016)
#pragma unroll
        for (int j = 0; j < 8; ++j) {
            const float logit = pf[j];
            pf[j] = lp[j * U_];                       // imm offset j*192 B

            const float4* sb = sbuf[j & 1];           // parity (t-1)&1 == j&1
            const float m = step_max_lds(sb, tc2);
            state = logit + m;                        // exact ref op order
            ((float*)sbuf[(j & 1) ^ 1])[u] = state;
            dp[j * U_] = state;                       // imm offset j*192 B
        }
        lp += 8 * U_;
        dp += 8 * U_;
    }

    // tail: t = 1017..1023 (7 steps); pf[0..6] hold rows 1017..1023
#pragma unroll
    for (int j = 0; j < 7; ++j) {
        const float logit = pf[j];
        const float4* sb = sbuf[j & 1];               // (t-1)=1016+j parity j&1
        const float m = step_max_lds(sb, tc2);
        state = logit + m;
        ((float*)sbuf[(j & 1) ^ 1])[u] = state;
        dp[j * U_] = state;
    }
}

// Fallback (in-place) variant if ws can't fit a second delta buffer.
__global__ __launch_bounds__(64, 1) void k_forward_inplace(const float* __restrict__ trans,
                                                           float* __restrict__ delta) {
    __shared__ float4 sbuf[2][U_ / 4];
    const int lane = threadIdx.x;
    const int b = blockIdx.x;
    const int u = (lane < U_) ? lane : (U_ - 1);

    float2 tc2[U_ / 2];
#pragma unroll
    for (int v = 0; v < U_; v += 2) {
        tc2[v / 2].x = trans[v * U_ + u];
        tc2[v / 2].y = trans[(v + 1) * U_ + u];
    }

    float* base = delta + (long)b * T_ * U_;
    float state = base[u];
    ((float*)sbuf[0])[u] = state;

#pragma unroll 1
    for (int t = 1; t < T_; ++t) {
        const float logit = base[(long)t * U_ + u];
        const float m = step_max_lds(sbuf[(t - 1) & 1], tc2);
        state = logit + m;
        ((float*)sbuf[t & 1])[u] = state;
        base[(long)t * U_ + u] = state;
    }
}

// ---------------------------------------------------------------------------
// K3: backpointers, R7 restructure: same LDS-broadcast pattern as k_forward
// (replaces readlane+SGPR-hazard chain). One wave per block; 32 contiguous
// rows per block; incremental (b,t) cursor (no per-row division); +1-row
// global prefetch. Strict-> ascending scan == numpy first-index tie-break;
// candidates bit-identical to K2's (same single add of same inputs).
// ---------------------------------------------------------------------------
#define BP_ROWS 32
__global__ __launch_bounds__(64, 1) void k_bp(const float* __restrict__ trans,
                                              const float* __restrict__ delta,
                                              unsigned char* __restrict__ bp) {
    __shared__ float sbuf[2][U_];         // row parity double buffer
    const int lane = threadIdx.x;
    const int u = (lane < U_) ? lane : (U_ - 1);

    float tc[U_];
#pragma unroll
    for (int v = 0; v < U_; ++v) tc[v] = trans[v * U_ + u];

    const int NROW = B_ * (T_ - 1);       // 130944
    const int row0 = blockIdx.x * BP_ROWS;
    if (row0 >= NROW) return;

    int b = row0 / (T_ - 1);              // uniform, once per block
    int tm1 = row0 - b * (T_ - 1);        // (t-1) in 0..1022

    float dval = delta[((long)b * T_ + tm1) * U_ + u];   // prefetch row0

#pragma unroll 1
    for (int i = 0; i < BP_ROWS; ++i) {
        const int row = row0 + i;
        if (row >= NROW) break;           // uniform guard

        sbuf[i & 1][u] = dval;            // stage current row (dup benign)

        // advance cursor, prefetch next row
        int bn = b, tn = tm1 + 1;
        if (tn == T_ - 1) { tn = 0; bn = b + 1; }
        float dnext = 0.0f;
        if (row + 1 < NROW) dnext = delta[((long)bn * T_ + tn) * U_ + u];

        const float4* sb4 = (const float4*)sbuf[i & 1];
        float best = -3.4e38f;
        int bi = 0;
#pragma unroll
        for (int k = 0; k < U_ / 4; ++k) {
            float4 s = sb4[k];            // uniform broadcast read
            float c0 = s.x + tc[4*k+0];
            float c1 = s.y + tc[4*k+1];
            float c2 = s.z + tc[4*k+2];
            float c3 = s.w + tc[4*k+3];
            bi = (c0 > best) ? 4*k+0 : bi;  best = fmaxf(best, c0);
            bi = (c1 > best) ? 4*k+1 : bi;  best = fmaxf(best, c1);
            bi = (c2 > best) ? 4*k+2 : bi;  best = fmaxf(best, c2);
            bi = (c3 > best) ? 4*k+3 : bi;  best = fmaxf(best, c3);
        }
        bp[(long)row * U_ + u] = (unsigned char)bi;   // dup-writes benign

        b = bn; tm1 = tn; dval = dnext;
    }
}

// ---------------------------------------------------------------------------
// K4: backtrace. One block per batch: stage bp[b] (48 KB) in LDS, argmax of
// final state (lane 0, strict-> ascending = first-index), chase through LDS,
// coalesced tag writeback.
// ---------------------------------------------------------------------------
__global__ __launch_bounds__(64) void k_back(const float* __restrict__ delta,
                                             const unsigned char* __restrict__ bp,
                                             float* __restrict__ out) {
    __shared__ unsigned char bpl[(T_ - 1) * U_];  // 49104 B
    __shared__ float tags[T_];                    // 4 KB
    __shared__ float fin[U_];
    const int lane = threadIdx.x;
    const int b = blockIdx.x;

    const uint32_t* src = (const uint32_t*)(bp + (long)b * (T_ - 1) * U_);
    uint32_t* dst = (uint32_t*)bpl;
    const int NW = (T_ - 1) * U_ / 4;             // 12276
    for (int i = lane; i < NW; i += 64) dst[i] = src[i];
    if (lane < U_) fin[lane] = delta[((long)b * T_ + (T_ - 1)) * U_ + lane];
    __syncthreads();

    if (lane == 0) {
        float best = fin[0];
        int tag = 0;
        for (int uu = 1; uu < U_; ++uu)
            if (fin[uu] > best) { best = fin[uu]; tag = uu; }
        tags[T_ - 1] = (float)tag;
        for (int t = T_ - 1; t >= 1; --t) {
            tag = bpl[(t - 1) * U_ + tag];
            tags[t - 1] = (float)tag;
        }
    }
    __syncthreads();

    float* o = out + (long)b * T_;
    for (int i = lane; i < T_; i += 64) o[i] = tags[i];
}

// ---------------------------------------------------------------------------
extern "C" void kernel_launch(void* const* d_in, const int* in_sizes, int n_in,
                              void* d_out, int out_size, void* d_ws, size_t ws_size,
                              hipStream_t stream) {
    const float* x     = (const float*)d_in[0];   // (B,T,D)
    const float* kern  = (const float*)d_in[1];   // (D,U)
    const float* bias  = (const float*)d_in[2];   // (U,)
    const float* trans = (const float*)d_in[3];   // (U,U)
    float* out = (float*)d_out;                   // (B,T) fp32 tags

    const size_t NBT = (size_t)B_ * T_ * U_ * sizeof(float);  // 25,165,824 B

    float* logits = (float*)d_ws;
    const bool two_buf = ws_size >= 2 * NBT + (size_t)B_ * T_ * U_;
    float* delta = two_buf ? (float*)((char*)d_ws + NBT) : logits;
    unsigned char* bp = (unsigned char*)d_ws + (two_buf ? 2 * NBT : NBT);

    const int NROW = B_ * (T_ - 1);
    const int bp_grid = (NROW + BP_ROWS - 1) / BP_ROWS;   // 4092

    k_logits<<<(B_ * T_ / 2) / 256, 256, 0, stream>>>(x, kern, bias, logits);
    if (two_buf)
        k_forward<<<B_, 64, 0, stream>>>(trans, logits, delta);
    else
        k_forward_inplace<<<B_, 64, 0, stream>>>(trans, logits);
    k_bp  <<<bp_grid, 64, 0, stream>>>(trans, delta, bp);
    k_back<<<B_,      64, 0, stream>>>(delta, bp, out);
}